// Round 4
// baseline (27.230 us; speedup 1.0000x reference)
//
#include <hip/hip_runtime.h>

#define Bq 32
#define Sq 8
#define Lq 128
#define Dq 768
#define Aq 10
#define Tq 8

constexpr int D4   = Dq / 4;     // 192 float4 columns
constexpr int NBS  = Bq * Sq;    // 256
constexpr int NBSA = NBS * Aq;   // 2560

// One block per (b,s). 6 waves: waves 0-2 stream the mean-pool (64 float4
// columns each), waves 3-5 handle arg sets pred/arg0/arg1. No __syncthreads
// anywhere (waves take disjoint paths), no LDS.
__global__ __launch_bounds__(384) void srl_fused_k(
    const int* __restrict__ sids, const float* __restrict__ mask,
    const float* __restrict__ emb, const int* __restrict__ pred,
    const int* __restrict__ a0, const int* __restrict__ a1,
    float* __restrict__ out)
{
    int bs   = blockIdx.x;          // 0..255
    int tid  = threadIdx.x;
    int wv   = tid >> 6;            // 0..5
    int lane = tid & 63;

    if (wv < 3) {
        // ---------------- mean pool: wave wv owns columns [wv*64, wv*64+64)
        // per-wave mask count via full butterfly (all lanes get the sum)
        float mv = mask[(size_t)bs * Lq + lane] +
                   mask[(size_t)bs * Lq + 64 + lane];
        for (int off = 32; off > 0; off >>= 1)
            mv += __shfl_xor(mv, off);
        float inv = 1.0f / fmaxf(mv, 1.0f);      // clip(count, 1, None)

        const float*  mrow = mask + (size_t)bs * Lq;   // uniform -> s_loads
        const float4* eb   = (const float4*)emb +
                             (size_t)bs * Lq * D4 + wv * 64 + lane;

        float4 acc = make_float4(0.f, 0.f, 0.f, 0.f);
#pragma unroll 16
        for (int l = 0; l < Lq; ++l) {
            float  m = mrow[l];                  // wave-uniform scalar load
            float4 v = eb[(size_t)l * D4];       // 1KB/wave, coalesced
            acc.x += v.x * m; acc.y += v.y * m;
            acc.z += v.z * m; acc.w += v.w * m;
        }
        float4 r = make_float4(acc.x * inv, acc.y * inv,
                               acc.z * inv, acc.w * inv);
        ((float4*)out)[(size_t)bs * D4 + wv * 64 + lane] = r;
        return;
    }

    // ---------------- arg embeddings: wave = set (0:pred 1:arg0 2:arg1) ---
    int set = wv - 3;
    const int* ids = (set == 0) ? pred : ((set == 1) ? a0 : a1);

    // whole sentence in 2 regs/lane
    int s0 = sids[(size_t)bs * Lq + lane];
    int s1 = sids[(size_t)bs * Lq + 64 + lane];

    const float4* eb = (const float4*)emb + (size_t)bs * Lq * D4;

    for (int a = 0; a < Aq; ++a) {
        int bsa = bs * Aq + a;
        int idv = (lane < Tq) ? ids[(size_t)bsa * Tq + lane] : 0;

        // last t (descending) whose nonzero id occurs in the sentence
        unsigned long long B0 = 0, B1 = 0;
        int ccount = 0;
#pragma unroll
        for (int t = Tq - 1; t >= 0; --t) {
            if (ccount == 0) {                       // wave-uniform
                int idt = __shfl(idv, t);
                if (idt != 0) {
                    unsigned long long b0 = __ballot(s0 == idt);
                    unsigned long long b1 = __ballot(s1 == idt);
                    int c = (int)(__popcll(b0) + __popcll(b1));
                    if (c > 0) { B0 = b0; B1 = b1; ccount = c; }
                }
            }
        }

        // gather matched rows (uniform bit loops, ascending l: deterministic)
        float4 acc0 = make_float4(0.f, 0.f, 0.f, 0.f);
        float4 acc1 = acc0, acc2 = acc0;
        unsigned long long b = B0;
        while (b) {
            int l = (int)__builtin_ctzll(b); b &= b - 1;
            float4 v0 = eb[(size_t)l * D4 + lane];
            float4 v1 = eb[(size_t)l * D4 + 64 + lane];
            float4 v2 = eb[(size_t)l * D4 + 128 + lane];
            acc0.x += v0.x; acc0.y += v0.y; acc0.z += v0.z; acc0.w += v0.w;
            acc1.x += v1.x; acc1.y += v1.y; acc1.z += v1.z; acc1.w += v1.w;
            acc2.x += v2.x; acc2.y += v2.y; acc2.z += v2.z; acc2.w += v2.w;
        }
        b = B1;
        while (b) {
            int l = (int)__builtin_ctzll(b) + 64; b &= b - 1;
            float4 v0 = eb[(size_t)l * D4 + lane];
            float4 v1 = eb[(size_t)l * D4 + 64 + lane];
            float4 v2 = eb[(size_t)l * D4 + 128 + lane];
            acc0.x += v0.x; acc0.y += v0.y; acc0.z += v0.z; acc0.w += v0.w;
            acc1.x += v1.x; acc1.y += v1.y; acc1.z += v1.z; acc1.w += v1.w;
            acc2.x += v2.x; acc2.y += v2.y; acc2.z += v2.z; acc2.w += v2.w;
        }

        float inv = (ccount > 0) ? 1.0f / (float)ccount : 0.0f;
        float4* o4 = (float4*)out +
                     ((size_t)NBS + (size_t)set * NBSA + bsa) * D4;
        o4[lane]       = make_float4(acc0.x*inv, acc0.y*inv, acc0.z*inv, acc0.w*inv);
        o4[64 + lane]  = make_float4(acc1.x*inv, acc1.y*inv, acc1.z*inv, acc1.w*inv);
        o4[128 + lane] = make_float4(acc2.x*inv, acc2.y*inv, acc2.z*inv, acc2.w*inv);
    }
}

extern "C" void kernel_launch(void* const* d_in, const int* in_sizes, int n_in,
                              void* d_out, int out_size, void* d_ws, size_t ws_size,
                              hipStream_t stream) {
    const int*   sids = (const int*)d_in[0];
    const float* mask = (const float*)d_in[1];
    const float* emb  = (const float*)d_in[2];
    const int*   pred = (const int*)d_in[3];
    const int*   a0   = (const int*)d_in[4];
    const int*   a1   = (const int*)d_in[5];
    float* out = (float*)d_out;

    srl_fused_k<<<NBS, 384, 0, stream>>>(sids, mask, emb, pred, a0, a1, out);
}